// Round 1
// baseline (2109.897 us; speedup 1.0000x reference)
//
#include <hip/hip_runtime.h>

#define HW 65536
#define IMG_ELEMS (2*64*65536)

// ---------------------------------------------------------------------------
// Kernel 1: t = PReLU( W[64,128] @ concat(image,guidance) + b , a_jbf )
// block = 256 threads, 1 pixel/thread, all 64 out channels in registers.
// Weights transposed in LDS as [k][c] so the c-loop vectorizes to b128 reads.
// ---------------------------------------------------------------------------
__global__ __launch_bounds__(256) void k_fuse1x1(
    const float* __restrict__ img, const float* __restrict__ gd,
    const float* __restrict__ w, const float* __restrict__ bias,
    const float* __restrict__ a, float* __restrict__ out)
{
    __shared__ float sW[128*64];   // [k][c]
    __shared__ float sB[64];
    int tid = threadIdx.x;
    for (int e = tid; e < 8192; e += 256) {
        int c = e >> 7, k = e & 127;
        sW[k*64 + c] = w[e];
    }
    if (tid < 64) sB[tid] = bias[tid];
    __syncthreads();

    int p  = blockIdx.x * 256 + tid;     // 0 .. 131071
    int b  = p >> 16, pp = p & 65535;
    const float* ib = img + (size_t)b*64*HW + pp;
    const float* gb = gd  + (size_t)b*64*HW + pp;

    float acc[64];
#pragma unroll
    for (int c = 0; c < 64; ++c) acc[c] = 0.f;

    for (int k = 0; k < 64; ++k) {
        float x = ib[(size_t)k*HW];
        const float* wr = &sW[k*64];
#pragma unroll
        for (int c = 0; c < 64; ++c) acc[c] = fmaf(wr[c], x, acc[c]);
    }
    for (int k = 0; k < 64; ++k) {
        float x = gb[(size_t)k*HW];
        const float* wr = &sW[(k+64)*64];
#pragma unroll
        for (int c = 0; c < 64; ++c) acc[c] = fmaf(wr[c], x, acc[c]);
    }

    float slope = a[0];
    float* ob = out + (size_t)b*64*HW + pp;
#pragma unroll
    for (int c = 0; c < 64; ++c) {
        float v = acc[c] + sB[c];
        v = (v >= 0.f) ? v : slope * v;
        ob[(size_t)c*HW] = v;
    }
}

// ---------------------------------------------------------------------------
// Kernel 2: 3x3 conv, C=64 -> 64, pad 1, stride 1.
// MODE 0: PReLU(a); MODE 2: + residual (no act).
// 16x16 spatial tile / block, 1 pixel/thread, 64 out-ch accumulators.
// ic chunks of 8; weights in LDS padded to tap-stride 12 (16B aligned b128).
// ---------------------------------------------------------------------------
template<int MODE>
__global__ __launch_bounds__(256) void k_conv3(
    const float* __restrict__ in, const float* __restrict__ w,
    const float* __restrict__ bias, const float* __restrict__ a,
    const float* __restrict__ res, float* __restrict__ out)
{
    __shared__ float sIn[8*324];     // [ic][18*18]
    __shared__ float sW[64*96];      // [oc][ic(8)][12]
    __shared__ float sB[64];

    int tid = threadIdx.x;
    int bz = blockIdx.z;
    int y0 = blockIdx.y * 16, x0 = blockIdx.x * 16;
    if (tid < 64) sB[tid] = bias[tid];

    float acc[64];
#pragma unroll
    for (int oc = 0; oc < 64; ++oc) acc[oc] = 0.f;

    int ty = tid >> 4, tx = tid & 15;
    const size_t ibase = (size_t)bz*64*HW;

    for (int ic0 = 0; ic0 < 64; ic0 += 8) {
        __syncthreads();
        // stage input 8 x 18 x 18 (zero-padded borders)
        for (int e = tid; e < 2592; e += 256) {
            int ic = e / 324, rem = e % 324;
            int r = rem / 18, c = rem % 18;
            int gy = y0 + r - 1, gx = x0 + c - 1;
            float v = 0.f;
            if (gy >= 0 && gy < 256 && gx >= 0 && gx < 256)
                v = in[ibase + (size_t)(ic0+ic)*HW + gy*256 + gx];
            sIn[e] = v;
        }
        // stage weights 64 x 8 x 9 -> [oc][ic][12]
        for (int e = tid; e < 4608; e += 256) {
            int oc = e / 72, rem = e % 72;
            int ic = rem / 9, tap = rem % 9;
            sW[oc*96 + ic*12 + tap] = w[(size_t)(oc*64 + ic0 + ic)*9 + tap];
        }
        __syncthreads();

        for (int ic = 0; ic < 8; ++ic) {
            float xv[9];
            const float* ib2 = &sIn[ic*324 + ty*18 + tx];
#pragma unroll
            for (int r = 0; r < 3; ++r)
#pragma unroll
                for (int c = 0; c < 3; ++c)
                    xv[r*3+c] = ib2[r*18 + c];
#pragma unroll
            for (int oc = 0; oc < 64; ++oc) {
                const float* wr = &sW[oc*96 + ic*12];
                float s = acc[oc];
                s = fmaf(wr[0], xv[0], s);
                s = fmaf(wr[1], xv[1], s);
                s = fmaf(wr[2], xv[2], s);
                s = fmaf(wr[3], xv[3], s);
                s = fmaf(wr[4], xv[4], s);
                s = fmaf(wr[5], xv[5], s);
                s = fmaf(wr[6], xv[6], s);
                s = fmaf(wr[7], xv[7], s);
                s = fmaf(wr[8], xv[8], s);
                acc[oc] = s;
            }
        }
    }

    int y = y0 + ty, x = x0 + tx;
    size_t obase = ibase + (size_t)y*256 + x;
    float slope = (MODE == 0) ? a[0] : 0.f;
#pragma unroll
    for (int oc = 0; oc < 64; ++oc) {
        float v = acc[oc] + sB[oc];
        if (MODE == 0) v = (v >= 0.f) ? v : slope * v;
        if (MODE == 2) v += res[obase + (size_t)oc*HW];
        out[obase + (size_t)oc*HW] = v;
    }
}

// ---------------------------------------------------------------------------
// Kernel 3: fused 1x1 conv C->576 (kg_w5) + dynamic-kernel combine.
// jbf[b,cc,y,x] = sum_kk  bi[q=kk*64+cc] * patch(q)  with
//   bi[q]    = b5[q] + sum_k w5[q][k] * y4[b,k,y,x]
//   patch(q) = image[b, q/9, y + (q%9)/3 - 1, x + (q%9)%3 - 1]  (zero pad)
// block = 256 threads = 64 pixels (8x8 tile) x 4 cc-groups of 16.
// Avoids materializing the 302 MB bi_kernel tensor.
// ---------------------------------------------------------------------------
__global__ __launch_bounds__(256) void k_jbf(
    const float* __restrict__ y4, const float* __restrict__ img,
    const float* __restrict__ w5, const float* __restrict__ b5,
    float* __restrict__ out)
{
    __shared__ float sY[64*64];    // [k][pix]
    __shared__ float sW5[64*64];   // [cc_local][k]
    __shared__ float sB5[576];

    int tid = threadIdx.x;
    int b = blockIdx.z;
    int y0 = blockIdx.y * 8, x0 = blockIdx.x * 8;
    size_t ibase = (size_t)b*64*HW;

    // stage y4 tile: all 64 channels x 64 pixels
    for (int e = tid; e < 4096; e += 256) {
        int k = e >> 6, pp = e & 63;
        int gy = y0 + (pp >> 3), gx = x0 + (pp & 7);
        sY[e] = y4[ibase + (size_t)k*HW + gy*256 + gx];
    }
    for (int e = tid; e < 576; e += 256) sB5[e] = b5[e];

    int pix = tid & 63, ccg = tid >> 6;      // wave-uniform cc-group
    int px = pix & 7, py = pix >> 3;
    int x = x0 + px, y = y0 + py;

    float jb[16];
#pragma unroll
    for (int i = 0; i < 16; ++i) jb[i] = 0.f;

    for (int kk = 0; kk < 9; ++kk) {
        __syncthreads();
        // stage w5 rows [kk*64, kk*64+64) x 64
        for (int e = tid; e < 4096; e += 256)
            sW5[e] = w5[(size_t)kk*4096 + e];
        __syncthreads();

        float acc2[16];
#pragma unroll
        for (int i = 0; i < 16; ++i) acc2[i] = 0.f;

        for (int k = 0; k < 64; k += 4) {
            float yv0 = sY[(k+0)*64 + pix];
            float yv1 = sY[(k+1)*64 + pix];
            float yv2 = sY[(k+2)*64 + pix];
            float yv3 = sY[(k+3)*64 + pix];
#pragma unroll
            for (int i = 0; i < 16; ++i) {
                const float* wr = &sW5[(ccg*16 + i)*64 + k];
                float s = acc2[i];
                s = fmaf(wr[0], yv0, s);
                s = fmaf(wr[1], yv1, s);
                s = fmaf(wr[2], yv2, s);
                s = fmaf(wr[3], yv3, s);
                acc2[i] = s;
            }
        }

#pragma unroll
        for (int i = 0; i < 16; ++i) {
            int cc = ccg*16 + i;
            int q = kk*64 + cc;
            float bi = acc2[i] + sB5[q];
            int ch = q / 9, tap = q % 9;
            int gy = y + tap/3 - 1, gx = x + (tap%3) - 1;
            float pv = 0.f;
            if (gy >= 0 && gy < 256 && gx >= 0 && gx < 256)
                pv = img[ibase + (size_t)ch*HW + gy*256 + gx];
            jb[i] = fmaf(bi, pv, jb[i]);
        }
    }

    size_t obase = ibase + (size_t)y*256 + x;
#pragma unroll
    for (int i = 0; i < 16; ++i) {
        int cc = ccg*16 + i;
        out[obase + (size_t)cc*HW] = jb[i];
    }
}

// ---------------------------------------------------------------------------
extern "C" void kernel_launch(void* const* d_in, const int* in_sizes, int n_in,
                              void* d_out, int out_size, void* d_ws, size_t ws_size,
                              hipStream_t stream) {
    const float* img  = (const float*)d_in[0];
    const float* gd   = (const float*)d_in[1];
    const float* tw   = (const float*)d_in[2];
    const float* tb   = (const float*)d_in[3];
    const float* ajbf = (const float*)d_in[4];
    const float* kw1  = (const float*)d_in[5];
    const float* kb1  = (const float*)d_in[6];
    const float* kw2  = (const float*)d_in[7];
    const float* kb2  = (const float*)d_in[8];
    const float* kw3  = (const float*)d_in[9];
    const float* kb3  = (const float*)d_in[10];
    const float* kw4  = (const float*)d_in[11];
    const float* kb4  = (const float*)d_in[12];
    const float* kw5  = (const float*)d_in[13];
    const float* kb5  = (const float*)d_in[14];
    const float* akg  = (const float*)d_in[15];
    const float* jw1  = (const float*)d_in[16];
    const float* jb1  = (const float*)d_in[17];
    const float* jw2  = (const float*)d_in[18];
    const float* jb2  = (const float*)d_in[19];
    float* out  = (float*)d_out;

    float* buf0 = (float*)d_ws;
    float* buf1 = buf0 + IMG_ELEMS;

    dim3 g3(16, 16, 2);   // conv3x3 tiles
    dim3 gj(32, 32, 2);   // jbf tiles

    // t = PReLU(1x1(concat(img, gd)), a_jbf)            -> buf0
    k_fuse1x1<<<512, 256, 0, stream>>>(img, gd, tw, tb, ajbf, buf0);
    // kg chain: 4x (3x3 + PReLU(a_kg))
    k_conv3<0><<<g3, 256, 0, stream>>>(buf0, kw1, kb1, akg, nullptr, buf1);
    k_conv3<0><<<g3, 256, 0, stream>>>(buf1, kw2, kb2, akg, nullptr, buf0);
    k_conv3<0><<<g3, 256, 0, stream>>>(buf0, kw3, kb3, akg, nullptr, buf1);
    k_conv3<0><<<g3, 256, 0, stream>>>(buf1, kw4, kb4, akg, nullptr, buf0);
    // fused kg_w5 (1x1 -> 576) + dynamic-kernel combine -> buf1
    k_jbf<<<gj, 256, 0, stream>>>(buf0, img, kw5, kb5, buf1);
    // jbf_conv: 3x3 + PReLU(a_jbf), then 3x3 + residual(image)
    k_conv3<0><<<g3, 256, 0, stream>>>(buf1, jw1, jb1, ajbf, nullptr, buf0);
    k_conv3<2><<<g3, 256, 0, stream>>>(buf0, jw2, jb2, ajbf, img, out);
}

// Round 2
// 751.880 us; speedup vs baseline: 2.8062x; 2.8062x over previous
//
#include <hip/hip_runtime.h>

#define HW 65536
#define IMG_ELEMS (2*64*65536)

typedef __bf16 bf16x8 __attribute__((ext_vector_type(8)));
typedef float f32x16 __attribute__((ext_vector_type(16)));

__device__ inline unsigned short f2bf(float x) {
    union { float f; unsigned u; } v; v.f = x;
    unsigned r = v.u + 0x7FFF + ((v.u >> 16) & 1);   // round-to-nearest-even
    return (unsigned short)(r >> 16);
}

union FragU { uint4 u; bf16x8 v; };
__device__ inline bf16x8 ld_frag(const uint4* p) { FragU t; t.u = *p; return t.v; }

// ---------------------------------------------------------------------------
// Weight pre-transform: w[oc][ic][tap] fp32  ->  wT[layer][tap][oc][ic] bf16
// ---------------------------------------------------------------------------
__global__ __launch_bounds__(256) void k_wprep(
    const float* __restrict__ w0, const float* __restrict__ w1,
    const float* __restrict__ w2, const float* __restrict__ w3,
    const float* __restrict__ w4, const float* __restrict__ w5,
    unsigned short* __restrict__ wT)
{
    const float* ws_[6] = {w0, w1, w2, w3, w4, w5};
    const float* w = ws_[blockIdx.y];
    unsigned short* o = wT + (size_t)blockIdx.y * 36864;
    for (int e = blockIdx.x * 256 + threadIdx.x; e < 36864; e += gridDim.x * 256) {
        int tap = e >> 12, oc = (e >> 6) & 63, ic = e & 63;
        o[e] = f2bf(w[(oc * 64 + ic) * 9 + tap]);
    }
}

// ---------------------------------------------------------------------------
// Kernel 1: t = PReLU( W[64,128] @ concat(image,guidance) + b , a_jbf )
// ---------------------------------------------------------------------------
__global__ __launch_bounds__(256) void k_fuse1x1(
    const float* __restrict__ img, const float* __restrict__ gd,
    const float* __restrict__ w, const float* __restrict__ bias,
    const float* __restrict__ a, float* __restrict__ out)
{
    __shared__ float sW[128*64];   // [k][c]
    __shared__ float sB[64];
    int tid = threadIdx.x;
    for (int e = tid; e < 8192; e += 256) {
        int c = e >> 7, k = e & 127;
        sW[k*64 + c] = w[e];
    }
    if (tid < 64) sB[tid] = bias[tid];
    __syncthreads();

    int p  = blockIdx.x * 256 + tid;
    int b  = p >> 16, pp = p & 65535;
    const float* ib = img + (size_t)b*64*HW + pp;
    const float* gb = gd  + (size_t)b*64*HW + pp;

    float acc[64];
#pragma unroll
    for (int c = 0; c < 64; ++c) acc[c] = 0.f;

    for (int k = 0; k < 64; ++k) {
        float x = ib[(size_t)k*HW];
        const float* wr = &sW[k*64];
#pragma unroll
        for (int c = 0; c < 64; ++c) acc[c] = fmaf(wr[c], x, acc[c]);
    }
    for (int k = 0; k < 64; ++k) {
        float x = gb[(size_t)k*HW];
        const float* wr = &sW[(k+64)*64];
#pragma unroll
        for (int c = 0; c < 64; ++c) acc[c] = fmaf(wr[c], x, acc[c]);
    }

    float slope = a[0];
    float* ob = out + (size_t)b*64*HW + pp;
#pragma unroll
    for (int c = 0; c < 64; ++c) {
        float v = acc[c] + sB[c];
        v = (v >= 0.f) ? v : slope * v;
        ob[(size_t)c*HW] = v;
    }
}

// ---------------------------------------------------------------------------
// Kernel 2: 3x3 conv C=64->64 pad 1 via bf16 MFMA (fp32 accumulate).
// MODE 0: PReLU(a); MODE 2: + residual (no act).
// Block: 256 thr = 4 waves; 16x16 px tile; wave computes 64oc x 64px as
// 2x2 tiles of v_mfma_f32_32x32x16_bf16.
// K = 576 ordered (ic_half, tap, ic16): per half stage input halo (bf16,
// channels-last padded) + all 9 taps' weights, then 18 K16-chunks.
// LDS: sX 25.9KB + sW 36.9KB -> 2 blocks/CU.
// ---------------------------------------------------------------------------
#define XU 5            // 16B units per (r,c) cell: 4 used + 1 pad (bank spread)

template<int MODE>
__global__ __launch_bounds__(256) void k_conv3m(
    const float* __restrict__ in, const unsigned short* __restrict__ wT,
    const float* __restrict__ bias, const float* __restrict__ a,
    const float* __restrict__ res, float* __restrict__ out)
{
    __shared__ uint4 sX[18*18*XU];     // halo tile, one ic-half, [r][c][ig][8]
    __shared__ uint4 sW[9*4*64];       // [tap][ig][oc][8] for current ic-half
    __shared__ float sB[64];

    int tid = threadIdx.x;
    int wv = tid >> 6, lane = tid & 63;
    int half = lane >> 5, l31 = lane & 31;
    int b = blockIdx.z;
    int y0 = blockIdx.y * 16, x0 = blockIdx.x * 16;
    const size_t ibase = (size_t)b * 64 * HW;

    if (tid < 64) sB[tid] = bias[tid];

    unsigned short* sXh = (unsigned short*)sX;

    f32x16 acc[2][2];
#pragma unroll
    for (int i = 0; i < 2; ++i)
#pragma unroll
        for (int j = 0; j < 2; ++j)
#pragma unroll
            for (int r = 0; r < 16; ++r) acc[i][j][r] = 0.f;

    for (int h = 0; h < 2; ++h) {
        __syncthreads();
        // stage input halo for this ic-half: fp32 -> bf16, channels-last
        for (int e = tid; e < 18*18*32; e += 256) {
            int ic = e / 324, rem = e % 324;
            int r = rem / 18, c = rem % 18;
            int gy = y0 + r - 1, gx = x0 + c - 1;
            float v = 0.f;
            if (gy >= 0 && gy < 256 && gx >= 0 && gx < 256)
                v = in[ibase + (size_t)(h*32 + ic)*HW + gy*256 + gx];
            int unit = (r*18 + c)*XU + (ic >> 3);
            sXh[unit*8 + (ic & 7)] = f2bf(v);
        }
        // stage weights: all 9 taps for this ic-half
        for (int ch = tid; ch < 2304; ch += 256) {
            // ch = (tap*4 + ig)*64 + oc
            int oc = ch & 63, tg = ch >> 6;
            int ig = tg & 3, tap = tg >> 2;
            sW[ch] = *(const uint4*)(wT + tap*4096 + oc*64 + h*32 + ig*8);
        }
        __syncthreads();

#pragma unroll
        for (int tap = 0; tap < 9; ++tap) {
            int dy = tap / 3, dx = tap % 3;
#pragma unroll
            for (int c = 0; c < 2; ++c) {
                int ig = c*2 + half;           // k = c*16 + half*8 + j
                // A frags: oc tiles 0 / 32
                bf16x8 a0 = ld_frag(&sW[(tap*4 + ig)*64 + l31]);
                bf16x8 a1 = ld_frag(&sW[(tap*4 + ig)*64 + 32 + l31]);
                // B frags: pixel tiles
                int p0 = wv*64 + l31;          // pt = 0
                int p1 = p0 + 32;              // pt = 1
                int u0 = ((( (p0>>4) + dy)*18) + (p0&15) + dx)*XU + ig;
                int u1 = ((( (p1>>4) + dy)*18) + (p1&15) + dx)*XU + ig;
                bf16x8 b0 = ld_frag(&sX[u0]);
                bf16x8 b1 = ld_frag(&sX[u1]);
                acc[0][0] = __builtin_amdgcn_mfma_f32_32x32x16_bf16(a0, b0, acc[0][0], 0, 0, 0);
                acc[0][1] = __builtin_amdgcn_mfma_f32_32x32x16_bf16(a0, b1, acc[0][1], 0, 0, 0);
                acc[1][0] = __builtin_amdgcn_mfma_f32_32x32x16_bf16(a1, b0, acc[1][0], 0, 0, 0);
                acc[1][1] = __builtin_amdgcn_mfma_f32_32x32x16_bf16(a1, b1, acc[1][1], 0, 0, 0);
            }
        }
    }

    float slope = (MODE == 0) ? a[0] : 0.f;
#pragma unroll
    for (int ot = 0; ot < 2; ++ot) {
#pragma unroll
        for (int pt = 0; pt < 2; ++pt) {
            int p = wv*64 + pt*32 + l31;
            int y = y0 + (p >> 4), x = x0 + (p & 15);
            size_t pbase = ibase + (size_t)y*256 + x;
#pragma unroll
            for (int r = 0; r < 16; ++r) {
                int oc = ot*32 + (r & 3) + 8*(r >> 2) + 4*half;
                float v = acc[ot][pt][r] + sB[oc];
                if (MODE == 0) v = (v >= 0.f) ? v : slope * v;
                if (MODE == 2) v += res[pbase + (size_t)oc*HW];
                out[pbase + (size_t)oc*HW] = v;
            }
        }
    }
}

// ---------------------------------------------------------------------------
// Kernel 3: fused 1x1 conv C->576 (kg_w5) + dynamic-kernel combine (fp32).
// ---------------------------------------------------------------------------
__global__ __launch_bounds__(256) void k_jbf(
    const float* __restrict__ y4, const float* __restrict__ img,
    const float* __restrict__ w5, const float* __restrict__ b5,
    float* __restrict__ out)
{
    __shared__ float sY[64*64];    // [k][pix]
    __shared__ float sW5[64*64];   // [cc_local][k]
    __shared__ float sB5[576];

    int tid = threadIdx.x;
    int b = blockIdx.z;
    int y0 = blockIdx.y * 8, x0 = blockIdx.x * 8;
    size_t ibase = (size_t)b*64*HW;

    for (int e = tid; e < 4096; e += 256) {
        int k = e >> 6, pp = e & 63;
        int gy = y0 + (pp >> 3), gx = x0 + (pp & 7);
        sY[e] = y4[ibase + (size_t)k*HW + gy*256 + gx];
    }
    for (int e = tid; e < 576; e += 256) sB5[e] = b5[e];

    int pix = tid & 63, ccg = tid >> 6;
    int px = pix & 7, py = pix >> 3;
    int x = x0 + px, y = y0 + py;

    float jb[16];
#pragma unroll
    for (int i = 0; i < 16; ++i) jb[i] = 0.f;

    for (int kk = 0; kk < 9; ++kk) {
        __syncthreads();
        for (int e = tid; e < 4096; e += 256)
            sW5[e] = w5[(size_t)kk*4096 + e];
        __syncthreads();

        float acc2[16];
#pragma unroll
        for (int i = 0; i < 16; ++i) acc2[i] = 0.f;

        for (int k = 0; k < 64; k += 4) {
            float yv0 = sY[(k+0)*64 + pix];
            float yv1 = sY[(k+1)*64 + pix];
            float yv2 = sY[(k+2)*64 + pix];
            float yv3 = sY[(k+3)*64 + pix];
#pragma unroll
            for (int i = 0; i < 16; ++i) {
                const float* wr = &sW5[(ccg*16 + i)*64 + k];
                float s = acc2[i];
                s = fmaf(wr[0], yv0, s);
                s = fmaf(wr[1], yv1, s);
                s = fmaf(wr[2], yv2, s);
                s = fmaf(wr[3], yv3, s);
                acc2[i] = s;
            }
        }

#pragma unroll
        for (int i = 0; i < 16; ++i) {
            int cc = ccg*16 + i;
            int q = kk*64 + cc;
            float bi = acc2[i] + sB5[q];
            int ch = q / 9, tap = q % 9;
            int gy = y + tap/3 - 1, gx = x + (tap%3) - 1;
            float pv = 0.f;
            if (gy >= 0 && gy < 256 && gx >= 0 && gx < 256)
                pv = img[ibase + (size_t)ch*HW + gy*256 + gx];
            jb[i] = fmaf(bi, pv, jb[i]);
        }
    }

    size_t obase = ibase + (size_t)y*256 + x;
#pragma unroll
    for (int i = 0; i < 16; ++i) {
        int cc = ccg*16 + i;
        out[obase + (size_t)cc*HW] = jb[i];
    }
}

// ---------------------------------------------------------------------------
extern "C" void kernel_launch(void* const* d_in, const int* in_sizes, int n_in,
                              void* d_out, int out_size, void* d_ws, size_t ws_size,
                              hipStream_t stream) {
    const float* img  = (const float*)d_in[0];
    const float* gd   = (const float*)d_in[1];
    const float* tw   = (const float*)d_in[2];
    const float* tb   = (const float*)d_in[3];
    const float* ajbf = (const float*)d_in[4];
    const float* kw1  = (const float*)d_in[5];
    const float* kb1  = (const float*)d_in[6];
    const float* kw2  = (const float*)d_in[7];
    const float* kb2  = (const float*)d_in[8];
    const float* kw3  = (const float*)d_in[9];
    const float* kb3  = (const float*)d_in[10];
    const float* kw4  = (const float*)d_in[11];
    const float* kb4  = (const float*)d_in[12];
    const float* kw5  = (const float*)d_in[13];
    const float* kb5  = (const float*)d_in[14];
    const float* akg  = (const float*)d_in[15];
    const float* jw1  = (const float*)d_in[16];
    const float* jb1  = (const float*)d_in[17];
    const float* jw2  = (const float*)d_in[18];
    const float* jb2  = (const float*)d_in[19];
    float* out  = (float*)d_out;

    float* bufA = (float*)d_ws;
    unsigned short* wT = (unsigned short*)((char*)d_ws + (size_t)IMG_ELEMS * 4);
    float* bufB = out;   // use d_out as ping-pong scratch until the final conv

    dim3 g3(16, 16, 2);
    dim3 gj(32, 32, 2);

    k_wprep<<<dim3(4, 6), 256, 0, stream>>>(kw1, kw2, kw3, kw4, jw1, jw2, wT);
    k_fuse1x1<<<512, 256, 0, stream>>>(img, gd, tw, tb, ajbf, bufA);

    k_conv3m<0><<<g3, 256, 0, stream>>>(bufA, wT + 0*36864, kb1, akg, nullptr, bufB);
    k_conv3m<0><<<g3, 256, 0, stream>>>(bufB, wT + 1*36864, kb2, akg, nullptr, bufA);
    k_conv3m<0><<<g3, 256, 0, stream>>>(bufA, wT + 2*36864, kb3, akg, nullptr, bufB);
    k_conv3m<0><<<g3, 256, 0, stream>>>(bufB, wT + 3*36864, kb4, akg, nullptr, bufA);

    k_jbf<<<gj, 256, 0, stream>>>(bufA, img, kw5, kb5, bufB);

    k_conv3m<0><<<g3, 256, 0, stream>>>(bufB, wT + 4*36864, jb1, ajbf, nullptr, bufA);
    k_conv3m<2><<<g3, 256, 0, stream>>>(bufA, wT + 5*36864, jb2, ajbf, img, out);
}

// Round 4
// 522.159 us; speedup vs baseline: 4.0407x; 1.4399x over previous
//
#include <hip/hip_runtime.h>

#define HW 65536

typedef __bf16 bf16x8 __attribute__((ext_vector_type(8)));
typedef float f32x16 __attribute__((ext_vector_type(16)));

__device__ inline unsigned short f2bf(float x) {
    union { float f; unsigned u; } v; v.f = x;
    unsigned r = v.u + 0x7FFF + ((v.u >> 16) & 1);   // round-to-nearest-even
    return (unsigned short)(r >> 16);
}

union FragU { uint4 u; bf16x8 v; };
__device__ inline bf16x8 ld_frag(const uint4* p) { FragU t; t.u = *p; return t.v; }

// ---------------------------------------------------------------------------
// Weight pre-transform (all to bf16):
//  layers 0..5 : conv3x3 w[oc][ic][tap] -> [tap][oc][ic]
//  layer  6    : kg_w5 [576][64] flat
//  layer  7    : tensor_w [64][128] flat
// ---------------------------------------------------------------------------
__global__ __launch_bounds__(256) void k_wprep(
    const float* __restrict__ w0, const float* __restrict__ w1,
    const float* __restrict__ w2, const float* __restrict__ w3,
    const float* __restrict__ w4, const float* __restrict__ w5,
    const float* __restrict__ w5c, const float* __restrict__ tw,
    unsigned short* __restrict__ wT)
{
    int y = blockIdx.y;
    unsigned short* o = wT + (size_t)y * 36864;
    if (y < 6) {
        const float* ws_[6] = {w0, w1, w2, w3, w4, w5};
        const float* w = ws_[y];
        for (int e = blockIdx.x * 256 + threadIdx.x; e < 36864; e += gridDim.x * 256) {
            int tap = e >> 12, oc = (e >> 6) & 63, ic = e & 63;
            o[e] = f2bf(w[(oc * 64 + ic) * 9 + tap]);
        }
    } else if (y == 6) {
        for (int e = blockIdx.x * 256 + threadIdx.x; e < 36864; e += gridDim.x * 256)
            o[e] = f2bf(w5c[e]);
    } else {
        for (int e = blockIdx.x * 256 + threadIdx.x; e < 8192; e += gridDim.x * 256)
            o[e] = f2bf(tw[e]);
    }
}

// ---------------------------------------------------------------------------
// Kernel 1: fuse 1x1 (2C->C) + PReLU via MFMA.  Tile 32x8 px, 4 waves.
// K=128 in 2 halves (img, gd).  Output bf16.
// ---------------------------------------------------------------------------
__global__ __launch_bounds__(256, 2) void k_fusem(
    const float* __restrict__ img, const float* __restrict__ gd,
    const unsigned short* __restrict__ wTf, const float* __restrict__ bias,
    const float* __restrict__ a, unsigned short* __restrict__ out)
{
    __shared__ uint4 sX[256*9];    // [p][ig(8)+pad]
    __shared__ uint4 sW[16*64];    // [kg][oc]
    __shared__ float sB[64];

    int tid = threadIdx.x;
    int wv = tid >> 6, lane = tid & 63;
    int half = lane >> 5, l31 = lane & 31;
    int b = blockIdx.z;
    int y0 = blockIdx.y * 8, x0 = blockIdx.x * 32;
    size_t ibase = (size_t)b * 64 * HW;

    for (int ch = tid; ch < 1024; ch += 256) {
        int kg = ch >> 6, oc = ch & 63;
        sW[ch] = ((const uint4*)wTf)[oc*16 + kg];
    }
    if (tid < 64) sB[tid] = bias[tid];

    unsigned short* sXh = (unsigned short*)sX;

    f32x16 acc[2][2];
#pragma unroll
    for (int i = 0; i < 2; ++i)
#pragma unroll
        for (int j = 0; j < 2; ++j)
#pragma unroll
            for (int r = 0; r < 16; ++r) acc[i][j][r] = 0.f;

    for (int h = 0; h < 2; ++h) {
        __syncthreads();
        const float* src = h ? gd : img;
        // stage ALL 64 channels x 256 px (16384 elements)
        for (int e = tid; e < 16384; e += 256) {
            int ic = e >> 8, p = e & 255;
            int gy = y0 + (p >> 5), gx = x0 + (p & 31);
            sXh[(p*9 + (ic >> 3))*8 + (ic & 7)] =
                f2bf(src[ibase + (size_t)ic*HW + gy*256 + gx]);
        }
        __syncthreads();
#pragma unroll
        for (int c = 0; c < 4; ++c) {
            int ig = c*2 + half;
            int kg = h*8 + ig;
            bf16x8 a0 = ld_frag(&sW[kg*64 + l31]);
            bf16x8 a1 = ld_frag(&sW[kg*64 + 32 + l31]);
            int p0 = wv*64 + l31;
            bf16x8 b0 = ld_frag(&sX[p0*9 + ig]);
            bf16x8 b1 = ld_frag(&sX[(p0+32)*9 + ig]);
            acc[0][0] = __builtin_amdgcn_mfma_f32_32x32x16_bf16(a0, b0, acc[0][0], 0, 0, 0);
            acc[0][1] = __builtin_amdgcn_mfma_f32_32x32x16_bf16(a0, b1, acc[0][1], 0, 0, 0);
            acc[1][0] = __builtin_amdgcn_mfma_f32_32x32x16_bf16(a1, b0, acc[1][0], 0, 0, 0);
            acc[1][1] = __builtin_amdgcn_mfma_f32_32x32x16_bf16(a1, b1, acc[1][1], 0, 0, 0);
        }
    }

    float slope = a[0];
#pragma unroll
    for (int ot = 0; ot < 2; ++ot)
#pragma unroll
        for (int pt = 0; pt < 2; ++pt) {
            int p = wv*64 + pt*32 + l31;
            int y = y0 + (p >> 5), x = x0 + (p & 31);
            size_t pbase = ibase + (size_t)y*256 + x;
#pragma unroll
            for (int r = 0; r < 16; ++r) {
                int oc = ot*32 + (r & 3) + 8*(r >> 2) + 4*half;
                float v = acc[ot][pt][r] + sB[oc];
                v = (v >= 0.f) ? v : slope * v;
                out[pbase + (size_t)oc*HW] = f2bf(v);
            }
        }
}

// ---------------------------------------------------------------------------
// Kernel 2: 3x3 conv C=64->64 pad 1, bf16 MFMA, bf16 in.
// MODE 0: PReLU + bf16 out; MODE 2: + fp32 residual, fp32 out.
// ---------------------------------------------------------------------------
#define XU 5

template<int MODE>
__global__ __launch_bounds__(256, 2) void k_conv3m(
    const unsigned short* __restrict__ in, const unsigned short* __restrict__ wT,
    const float* __restrict__ bias, const float* __restrict__ a,
    const float* __restrict__ res, void* __restrict__ outv)
{
    __shared__ uint4 sX[18*18*XU];     // [r][c][ig(4)+pad]
    __shared__ uint4 sW[9*4*64];       // [tap][ig][oc]
    __shared__ float sB[64];

    int tid = threadIdx.x;
    int wv = tid >> 6, lane = tid & 63;
    int half = lane >> 5, l31 = lane & 31;
    int b = blockIdx.z;
    int y0 = blockIdx.y * 16, x0 = blockIdx.x * 16;
    const size_t ibase = (size_t)b * 64 * HW;

    if (tid < 64) sB[tid] = bias[tid];

    unsigned short* sXh = (unsigned short*)sX;

    f32x16 acc[2][2];
#pragma unroll
    for (int i = 0; i < 2; ++i)
#pragma unroll
        for (int j = 0; j < 2; ++j)
#pragma unroll
            for (int r = 0; r < 16; ++r) acc[i][j][r] = 0.f;

    for (int h = 0; h < 2; ++h) {
        __syncthreads();
        for (int e = tid; e < 18*18*32; e += 256) {
            int ic = e / 324, rem = e % 324;
            int r = rem / 18, c = rem % 18;
            int gy = y0 + r - 1, gx = x0 + c - 1;
            unsigned short v = 0;
            if (gy >= 0 && gy < 256 && gx >= 0 && gx < 256)
                v = in[ibase + (size_t)(h*32 + ic)*HW + gy*256 + gx];
            int unit = (r*18 + c)*XU + (ic >> 3);
            sXh[unit*8 + (ic & 7)] = v;
        }
        for (int ch = tid; ch < 2304; ch += 256) {
            int oc = ch & 63, tg = ch >> 6;
            int ig = tg & 3, tap = tg >> 2;
            sW[ch] = *(const uint4*)(wT + tap*4096 + oc*64 + h*32 + ig*8);
        }
        __syncthreads();

#pragma unroll
        for (int tap = 0; tap < 9; ++tap) {
            int dy = tap / 3, dx = tap % 3;
#pragma unroll
            for (int c = 0; c < 2; ++c) {
                int ig = c*2 + half;
                bf16x8 a0 = ld_frag(&sW[(tap*4 + ig)*64 + l31]);
                bf16x8 a1 = ld_frag(&sW[(tap*4 + ig)*64 + 32 + l31]);
                int p0 = wv*64 + l31;
                int p1 = p0 + 32;
                int u0 = ((( (p0>>4) + dy)*18) + (p0&15) + dx)*XU + ig;
                int u1 = ((( (p1>>4) + dy)*18) + (p1&15) + dx)*XU + ig;
                bf16x8 b0 = ld_frag(&sX[u0]);
                bf16x8 b1 = ld_frag(&sX[u1]);
                acc[0][0] = __builtin_amdgcn_mfma_f32_32x32x16_bf16(a0, b0, acc[0][0], 0, 0, 0);
                acc[0][1] = __builtin_amdgcn_mfma_f32_32x32x16_bf16(a0, b1, acc[0][1], 0, 0, 0);
                acc[1][0] = __builtin_amdgcn_mfma_f32_32x32x16_bf16(a1, b0, acc[1][0], 0, 0, 0);
                acc[1][1] = __builtin_amdgcn_mfma_f32_32x32x16_bf16(a1, b1, acc[1][1], 0, 0, 0);
            }
        }
    }

    float slope = (MODE == 0) ? a[0] : 0.f;
#pragma unroll
    for (int ot = 0; ot < 2; ++ot) {
#pragma unroll
        for (int pt = 0; pt < 2; ++pt) {
            int p = wv*64 + pt*32 + l31;
            int y = y0 + (p >> 4), x = x0 + (p & 15);
            size_t pbase = ibase + (size_t)y*256 + x;
#pragma unroll
            for (int r = 0; r < 16; ++r) {
                int oc = ot*32 + (r & 3) + 8*(r >> 2) + 4*half;
                float v = acc[ot][pt][r] + sB[oc];
                if (MODE == 0) {
                    v = (v >= 0.f) ? v : slope * v;
                    ((unsigned short*)outv)[pbase + (size_t)oc*HW] = f2bf(v);
                } else {
                    v += res[pbase + (size_t)oc*HW];
                    ((float*)outv)[pbase + (size_t)oc*HW] = v;
                }
            }
        }
    }
}

// ---------------------------------------------------------------------------
// Kernel 3: fused kg_w5 1x1 (C->576) + dynamic-kernel combine, MFMA version.
// ---------------------------------------------------------------------------
__global__ __launch_bounds__(256, 2) void k_jbfm(
    const unsigned short* __restrict__ y4, const float* __restrict__ img,
    const unsigned short* __restrict__ w5T, const float* __restrict__ b5,
    unsigned short* __restrict__ out)
{
    __shared__ uint4 sY[256*9];     // [p][ig(8)+pad]
    __shared__ uint4 sW5[8*64];     // [ig][cc] for current kk
    __shared__ float sImg[8*340];   // [ch(8)][hr(10)][hc(34)] for current kk
    __shared__ float sB5[576];

    int tid = threadIdx.x;
    int wv = tid >> 6, lane = tid & 63;
    int half = lane >> 5, l31 = lane & 31;
    int b = blockIdx.z;
    int y0 = blockIdx.y * 8, x0 = blockIdx.x * 32;
    size_t ibase = (size_t)b * 64 * HW;

    unsigned short* sYh = (unsigned short*)sY;
    // stage ALL 64 channels x 256 px (16384 elements)
    for (int e = tid; e < 16384; e += 256) {
        int ic = e >> 8, p = e & 255;
        int gy = y0 + (p >> 5), gx = x0 + (p & 31);
        sYh[(p*9 + (ic >> 3))*8 + (ic & 7)] =
            y4[ibase + (size_t)ic*HW + gy*256 + gx];
    }
    for (int e = tid; e < 576; e += 256) sB5[e] = b5[e];

    float jb[2][2][16];
#pragma unroll
    for (int i = 0; i < 2; ++i)
#pragma unroll
        for (int j = 0; j < 2; ++j)
#pragma unroll
            for (int r = 0; r < 16; ++r) jb[i][j][r] = 0.f;

#pragma unroll
    for (int kk = 0; kk < 9; ++kk) {
        const int chlo = (kk*64)/9;
        __syncthreads();
        for (int u = tid; u < 512; u += 256) {
            int cc = u & 63, ig = u >> 6;
            sW5[u] = ((const uint4*)w5T)[(kk*64 + cc)*8 + ig];
        }
        for (int e = tid; e < 2720; e += 256) {
            int ch = e / 340, rem = e - ch*340;
            int rr = rem / 34, c2 = rem - rr*34;
            int gy = y0 + rr - 1, gx = x0 + c2 - 1;
            float v = 0.f;
            if (gy >= 0 && gy < 256 && gx >= 0 && gx < 256)
                v = img[ibase + (size_t)(chlo + ch)*HW + gy*256 + gx];
            sImg[e] = v;
        }
        __syncthreads();

        // bias-init accumulators (C-input of first MFMA)
        f32x16 acc[2][2];
#pragma unroll
        for (int ot = 0; ot < 2; ++ot)
#pragma unroll
            for (int r = 0; r < 16; ++r) {
                int cc0 = ot*32 + (r & 3) + 8*(r >> 2);
                float bv = sB5[kk*64 + cc0 + 4*half];
                acc[ot][0][r] = bv;
                acc[ot][1][r] = bv;
            }

#pragma unroll
        for (int c = 0; c < 4; ++c) {
            int ig = c*2 + half;
            bf16x8 a0 = ld_frag(&sW5[ig*64 + l31]);
            bf16x8 a1 = ld_frag(&sW5[ig*64 + 32 + l31]);
            int p0 = wv*64 + l31;
            bf16x8 b0 = ld_frag(&sY[p0*9 + ig]);
            bf16x8 b1 = ld_frag(&sY[(p0+32)*9 + ig]);
            acc[0][0] = __builtin_amdgcn_mfma_f32_32x32x16_bf16(a0, b0, acc[0][0], 0, 0, 0);
            acc[0][1] = __builtin_amdgcn_mfma_f32_32x32x16_bf16(a0, b1, acc[0][1], 0, 0, 0);
            acc[1][0] = __builtin_amdgcn_mfma_f32_32x32x16_bf16(a1, b0, acc[1][0], 0, 0, 0);
            acc[1][1] = __builtin_amdgcn_mfma_f32_32x32x16_bf16(a1, b1, acc[1][1], 0, 0, 0);
        }

        // combine: jb += bi * patch
#pragma unroll
        for (int ot = 0; ot < 2; ++ot)
#pragma unroll
            for (int pt = 0; pt < 2; ++pt) {
                int py = wv*2 + pt;
                const float* base = &sImg[py*34 + l31];
#pragma unroll
                for (int r = 0; r < 16; ++r) {
                    const int cc0 = ot*32 + (r & 3) + 8*(r >> 2);
                    const int q0 = kk*64 + cc0, q1 = q0 + 4;
                    const int o0 = (q0/9 - chlo)*340 + ((q0%9)/3)*34 + (q0%9)%3;
                    const int o1 = (q1/9 - chlo)*340 + ((q1%9)/3)*34 + (q1%9)%3;
                    float pv = base[half ? o1 : o0];
                    jb[ot][pt][r] = fmaf(acc[ot][pt][r], pv, jb[ot][pt][r]);
                }
            }
    }

#pragma unroll
    for (int ot = 0; ot < 2; ++ot)
#pragma unroll
        for (int pt = 0; pt < 2; ++pt) {
            int p = wv*64 + pt*32 + l31;
            int y = y0 + (p >> 5), x = x0 + (p & 31);
            size_t pbase = ibase + (size_t)y*256 + x;
#pragma unroll
            for (int r = 0; r < 16; ++r) {
                int cc = ot*32 + (r & 3) + 8*(r >> 2) + 4*half;
                out[pbase + (size_t)cc*HW] = f2bf(jb[ot][pt][r]);
            }
        }
}

// ---------------------------------------------------------------------------
extern "C" void kernel_launch(void* const* d_in, const int* in_sizes, int n_in,
                              void* d_out, int out_size, void* d_ws, size_t ws_size,
                              hipStream_t stream) {
    const float* img  = (const float*)d_in[0];
    const float* gd   = (const float*)d_in[1];
    const float* tw   = (const float*)d_in[2];
    const float* tb   = (const float*)d_in[3];
    const float* ajbf = (const float*)d_in[4];
    const float* kw1  = (const float*)d_in[5];
    const float* kb1  = (const float*)d_in[6];
    const float* kw2  = (const float*)d_in[7];
    const float* kb2  = (const float*)d_in[8];
    const float* kw3  = (const float*)d_in[9];
    const float* kb3  = (const float*)d_in[10];
    const float* kw4  = (const float*)d_in[11];
    const float* kb4  = (const float*)d_in[12];
    const float* kw5  = (const float*)d_in[13];
    const float* kb5  = (const float*)d_in[14];
    const float* akg  = (const float*)d_in[15];
    const float* jw1  = (const float*)d_in[16];
    const float* jb1  = (const float*)d_in[17];
    const float* jw2  = (const float*)d_in[18];
    const float* jb2  = (const float*)d_in[19];
    float* out  = (float*)d_out;

    unsigned short* bufA = (unsigned short*)d_ws;
    unsigned short* wT   = (unsigned short*)((char*)d_ws + (size_t)2*64*HW*2 + 256);
    unsigned short* bufB = (unsigned short*)d_out;  // d_out as bf16 scratch until final conv

    dim3 g3(16, 16, 2);   // conv3x3: 16x16 tiles
    dim3 gw(8, 32, 2);    // fuse/jbf: 32x8 tiles

    k_wprep<<<dim3(4, 8), 256, 0, stream>>>(kw1, kw2, kw3, kw4, jw1, jw2, kw5, tw, wT);
    k_fusem<<<gw, 256, 0, stream>>>(img, gd, wT + (size_t)7*36864, tb, ajbf, bufA);

    k_conv3m<0><<<g3, 256, 0, stream>>>(bufA, wT + (size_t)0*36864, kb1, akg, nullptr, bufB);
    k_conv3m<0><<<g3, 256, 0, stream>>>(bufB, wT + (size_t)1*36864, kb2, akg, nullptr, bufA);
    k_conv3m<0><<<g3, 256, 0, stream>>>(bufA, wT + (size_t)2*36864, kb3, akg, nullptr, bufB);
    k_conv3m<0><<<g3, 256, 0, stream>>>(bufB, wT + (size_t)3*36864, kb4, akg, nullptr, bufA);

    k_jbfm<<<gw, 256, 0, stream>>>(bufA, img, wT + (size_t)6*36864, kb5, bufB);

    k_conv3m<0><<<g3, 256, 0, stream>>>(bufB, wT + (size_t)4*36864, jb1, ajbf, nullptr, bufA);
    k_conv3m<2><<<g3, 256, 0, stream>>>(bufA, wT + (size_t)5*36864, jb2, ajbf, img, out);
}

// Round 5
// 354.440 us; speedup vs baseline: 5.9528x; 1.4732x over previous
//
#include <hip/hip_runtime.h>

#define HW 65536

typedef __bf16 bf16x8 __attribute__((ext_vector_type(8)));
typedef float f32x16 __attribute__((ext_vector_type(16)));

__device__ inline unsigned short f2bf(float x) {
    union { float f; unsigned u; } v; v.f = x;
    unsigned r = v.u + 0x7FFF + ((v.u >> 16) & 1);   // RNE
    return (unsigned short)(r >> 16);
}
__device__ inline float bfhi2f(unsigned u) {        // high 16 bits as f32
    union { unsigned u; float f; } v; v.u = u & 0xffff0000u; return v.f;
}
__device__ inline float bflo2f(unsigned u) {        // low 16 bits as f32
    union { unsigned u; float f; } v; v.u = u << 16; return v.f;
}

union FragU { uint4 u; bf16x8 v; };
__device__ inline bf16x8 ld_frag(const uint4* p) { FragU t; t.u = *p; return t.v; }

// ---------------------------------------------------------------------------
// Weight pre-transform (unchanged from round 4).
// ---------------------------------------------------------------------------
__global__ __launch_bounds__(256) void k_wprep(
    const float* __restrict__ w0, const float* __restrict__ w1,
    const float* __restrict__ w2, const float* __restrict__ w3,
    const float* __restrict__ w4, const float* __restrict__ w5,
    const float* __restrict__ w5c, const float* __restrict__ tw,
    unsigned short* __restrict__ wT)
{
    int y = blockIdx.y;
    unsigned short* o = wT + (size_t)y * 36864;
    if (y < 6) {
        const float* ws_[6] = {w0, w1, w2, w3, w4, w5};
        const float* w = ws_[y];
        for (int e = blockIdx.x * 256 + threadIdx.x; e < 36864; e += gridDim.x * 256) {
            int tap = e >> 12, oc = (e >> 6) & 63, ic = e & 63;
            o[e] = f2bf(w[(oc * 64 + ic) * 9 + tap]);
        }
    } else if (y == 6) {
        for (int e = blockIdx.x * 256 + threadIdx.x; e < 36864; e += gridDim.x * 256)
            o[e] = f2bf(w5c[e]);
    } else {
        for (int e = blockIdx.x * 256 + threadIdx.x; e < 8192; e += gridDim.x * 256)
            o[e] = f2bf(tw[e]);
    }
}

// ---------------------------------------------------------------------------
// k_tr: NCHW fp32 -> NHWC bf16 for img and guidance (64-px x 64-ch tiles).
// ---------------------------------------------------------------------------
__global__ __launch_bounds__(256) void k_tr(
    const float* __restrict__ img, const float* __restrict__ gd,
    unsigned short* __restrict__ imgT, unsigned short* __restrict__ gdT)
{
    __shared__ float sT[64 * 66];   // [ic][66] fp32 (stride 66 -> spread reads)
    int tid = threadIdx.x;
    int z = blockIdx.y;             // tensor*2 + b
    int b = z & 1;
    const float* src = (z >> 1) ? gd : img;
    unsigned short* dst = (z >> 1) ? gdT : imgT;
    int px0 = blockIdx.x * 64;
    size_t sbase = (size_t)b * 64 * HW + px0;

#pragma unroll
    for (int i = 0; i < 4; ++i) {
        int e = i * 256 + tid;                 // [0,1024)
        int ic = e >> 4, seg = e & 15;
        float4 v = *(const float4*)(src + sbase + (size_t)ic * HW + seg * 4);
        float* p = &sT[ic * 66 + seg * 4];
        ((float2*)p)[0] = make_float2(v.x, v.y);
        ((float2*)p)[1] = make_float2(v.z, v.w);
    }
    __syncthreads();

    size_t dbase = (size_t)b * HW * 64 + (size_t)px0 * 64;
#pragma unroll
    for (int k = 0; k < 2; ++k) {
        int idx = k * 256 + tid;               // [0,512)
        int px = idx >> 3, u = idx & 7;
        union { uint4 q; unsigned short h[8]; } o;
#pragma unroll
        for (int j = 0; j < 8; ++j)
            o.h[j] = f2bf(sT[(u * 8 + j) * 66 + px]);
        *(uint4*)(dst + dbase + (size_t)px * 64 + u * 8) = o.q;
    }
}

// ---------------------------------------------------------------------------
// k_fusem: 1x1 (2C->C) + PReLU. NHWC bf16 in (imgT, gdT), NHWC bf16 out.
// Tile 32x8 px, 4 waves, 2x2 MFMA 32x32x16.
// ---------------------------------------------------------------------------
__global__ __launch_bounds__(256, 2) void k_fusem(
    const unsigned short* __restrict__ imgT, const unsigned short* __restrict__ gdT,
    const unsigned short* __restrict__ wTf, const float* __restrict__ bias,
    const float* __restrict__ a, unsigned short* __restrict__ out)
{
    __shared__ __align__(16) char smem[53504];
    uint4* sX = (uint4*)smem;                     // 2304 uint4: [px][ig 0..8(pad)]
    uint4* sW = (uint4*)(smem + 36864);           // 1024 uint4: [kg][oc]
    float* sB = (float*)(smem + 53248);
    unsigned short* sT16 = (unsigned short*)smem; // epilogue overlay 32KB

    int tid = threadIdx.x;
    int wv = tid >> 6, lane = tid & 63;
    int half = lane >> 5, l31 = lane & 31;
    int b = blockIdx.z;
    int y0 = blockIdx.y * 8, x0 = blockIdx.x * 32;
    size_t zbase = (size_t)b * HW * 64;

    for (int ch = tid; ch < 1024; ch += 256) {
        int kg = ch >> 6, oc = ch & 63;
        sW[ch] = ((const uint4*)wTf)[oc * 16 + kg];
    }
    if (tid < 64) sB[tid] = bias[tid];

    f32x16 acc[2][2];
#pragma unroll
    for (int i = 0; i < 2; ++i)
#pragma unroll
        for (int j = 0; j < 2; ++j)
#pragma unroll
            for (int r = 0; r < 16; ++r) acc[i][j][r] = 0.f;

    for (int h = 0; h < 2; ++h) {
        __syncthreads();
        const unsigned short* src = h ? gdT : imgT;
#pragma unroll
        for (int i = 0; i < 8; ++i) {
            int e = i * 256 + tid;                 // [0,2048)
            int px = e >> 3, ig = e & 7;
            int gy = y0 + (px >> 5), gx = x0 + (px & 31);
            uint4 v = *(const uint4*)(src + zbase + ((size_t)(gy * 256 + gx)) * 64 + ig * 8);
            sX[px * 9 + ig] = v;
        }
        __syncthreads();
#pragma unroll
        for (int c = 0; c < 4; ++c) {
            int ig = c * 2 + half;
            int kg = h * 8 + ig;
            bf16x8 a0 = ld_frag(&sW[kg * 64 + l31]);
            bf16x8 a1 = ld_frag(&sW[kg * 64 + 32 + l31]);
            int p0 = wv * 64 + l31;
            bf16x8 b0 = ld_frag(&sX[p0 * 9 + ig]);
            bf16x8 b1 = ld_frag(&sX[(p0 + 32) * 9 + ig]);
            acc[0][0] = __builtin_amdgcn_mfma_f32_32x32x16_bf16(a0, b0, acc[0][0], 0, 0, 0);
            acc[0][1] = __builtin_amdgcn_mfma_f32_32x32x16_bf16(a0, b1, acc[0][1], 0, 0, 0);
            acc[1][0] = __builtin_amdgcn_mfma_f32_32x32x16_bf16(a1, b0, acc[1][0], 0, 0, 0);
            acc[1][1] = __builtin_amdgcn_mfma_f32_32x32x16_bf16(a1, b1, acc[1][1], 0, 0, 0);
        }
    }

    float slope = a[0];
    __syncthreads();   // before overwriting sX region with epilogue tile
#pragma unroll
    for (int ot = 0; ot < 2; ++ot)
#pragma unroll
        for (int pt = 0; pt < 2; ++pt) {
            int px = wv * 64 + pt * 32 + l31;
#pragma unroll
            for (int q2 = 0; q2 < 4; ++q2) {
                unsigned short hw[4];
#pragma unroll
                for (int j = 0; j < 4; ++j) {
                    int r = (q2 << 2) | j;
                    int oc = ot * 32 + j + 8 * q2 + 4 * half;
                    float v = acc[ot][pt][r] + sB[oc];
                    v = (v >= 0.f) ? v : slope * v;
                    hw[j] = f2bf(v);
                }
                int unit = ot * 4 + q2;
                int up = unit ^ (px & 7);
                uint2* p = (uint2*)&sT16[px * 64 + up * 8 + half * 4];
                *p = make_uint2((unsigned)hw[0] | ((unsigned)hw[1] << 16),
                                (unsigned)hw[2] | ((unsigned)hw[3] << 16));
            }
        }
    __syncthreads();
#pragma unroll
    for (int k = 0; k < 8; ++k) {               // row k of 32x8 tile
        int col = tid >> 3, u = tid & 7;
        int px = k * 32 + col;
        uint4 v = *(uint4*)&sT16[px * 64 + (u ^ (px & 7)) * 8];
        *(uint4*)(out + zbase + ((size_t)((y0 + k) * 256 + x0 + col)) * 64 + u * 8) = v;
    }
}

// ---------------------------------------------------------------------------
// k_conv3m: 3x3 conv C=64->64 pad 1, bf16 MFMA, NHWC bf16 in.
// MODE 0: PReLU, NHWC bf16 out.  MODE 2: + fp32 residual, NCHW fp32 out.
// 16x16 px tile, ic-halves, XU=5 padded halo cells.
// ---------------------------------------------------------------------------
#define XU 5

template<int MODE>
__global__ __launch_bounds__(256, 2) void k_conv3m(
    const unsigned short* __restrict__ in, const unsigned short* __restrict__ wT,
    const float* __restrict__ bias, const float* __restrict__ a,
    const float* __restrict__ res, void* __restrict__ outv)
{
    __shared__ __align__(16) char smem[63040];
    uint4* sX = (uint4*)smem;                     // 1620 uint4: [cell][ig 0..3 +pad]
    uint4* sW = (uint4*)(smem + 25920);           // 2304 uint4: [tap][ig][oc]
    float* sB = (float*)(smem + 62784);
    unsigned short* sT16 = (unsigned short*)smem; // epilogue overlay 32KB (MODE 0)

    int tid = threadIdx.x;
    int wv = tid >> 6, lane = tid & 63;
    int half = lane >> 5, l31 = lane & 31;
    int b = blockIdx.z;
    int y0 = blockIdx.y * 16, x0 = blockIdx.x * 16;
    const size_t zbase = (size_t)b * HW * 64;

    if (tid < 64) sB[tid] = bias[tid];

    f32x16 acc[2][2];
#pragma unroll
    for (int i = 0; i < 2; ++i)
#pragma unroll
        for (int j = 0; j < 2; ++j)
#pragma unroll
            for (int r = 0; r < 16; ++r) acc[i][j][r] = 0.f;

    for (int h = 0; h < 2; ++h) {
        __syncthreads();
        // stage halo: 18x18 cells x 4 uint4 (32 ch of this half)
#pragma unroll
        for (int i = 0; i < 6; ++i) {
            int e = i * 256 + tid;
            if (e < 1296) {
                int cell = e >> 2, ig = e & 3;
                int r = cell / 18, c = cell - r * 18;
                int gy = y0 + r - 1, gx = x0 + c - 1;
                uint4 v = make_uint4(0, 0, 0, 0);
                if (gy >= 0 && gy < 256 && gx >= 0 && gx < 256)
                    v = *(const uint4*)(in + zbase + ((size_t)(gy * 256 + gx)) * 64 + h * 32 + ig * 8);
                sX[cell * XU + ig] = v;
            }
        }
        for (int ch = tid; ch < 2304; ch += 256) {
            int oc = ch & 63, tg = ch >> 6;
            int ig = tg & 3, tap = tg >> 2;
            sW[ch] = *(const uint4*)(wT + tap * 4096 + oc * 64 + h * 32 + ig * 8);
        }
        __syncthreads();

#pragma unroll
        for (int tap = 0; tap < 9; ++tap) {
            int dy = tap / 3, dx = tap % 3;
#pragma unroll
            for (int c = 0; c < 2; ++c) {
                int ig = c * 2 + half;
                bf16x8 a0 = ld_frag(&sW[(tap * 4 + ig) * 64 + l31]);
                bf16x8 a1 = ld_frag(&sW[(tap * 4 + ig) * 64 + 32 + l31]);
                int p0 = wv * 64 + l31;
                int p1 = p0 + 32;
                int u0 = ((((p0 >> 4) + dy) * 18) + (p0 & 15) + dx) * XU + ig;
                int u1 = ((((p1 >> 4) + dy) * 18) + (p1 & 15) + dx) * XU + ig;
                bf16x8 b0 = ld_frag(&sX[u0]);
                bf16x8 b1 = ld_frag(&sX[u1]);
                acc[0][0] = __builtin_amdgcn_mfma_f32_32x32x16_bf16(a0, b0, acc[0][0], 0, 0, 0);
                acc[0][1] = __builtin_amdgcn_mfma_f32_32x32x16_bf16(a0, b1, acc[0][1], 0, 0, 0);
                acc[1][0] = __builtin_amdgcn_mfma_f32_32x32x16_bf16(a1, b0, acc[1][0], 0, 0, 0);
                acc[1][1] = __builtin_amdgcn_mfma_f32_32x32x16_bf16(a1, b1, acc[1][1], 0, 0, 0);
            }
        }
    }

    if (MODE == 0) {
        float slope = a[0];
        __syncthreads();
#pragma unroll
        for (int ot = 0; ot < 2; ++ot)
#pragma unroll
            for (int pt = 0; pt < 2; ++pt) {
                int px = wv * 64 + pt * 32 + l31;
#pragma unroll
                for (int q2 = 0; q2 < 4; ++q2) {
                    unsigned short hw[4];
#pragma unroll
                    for (int j = 0; j < 4; ++j) {
                        int r = (q2 << 2) | j;
                        int oc = ot * 32 + j + 8 * q2 + 4 * half;
                        float v = acc[ot][pt][r] + sB[oc];
                        v = (v >= 0.f) ? v : slope * v;
                        hw[j] = f2bf(v);
                    }
                    int unit = ot * 4 + q2;
                    int up = unit ^ (px & 7);
                    uint2* p = (uint2*)&sT16[px * 64 + up * 8 + half * 4];
                    *p = make_uint2((unsigned)hw[0] | ((unsigned)hw[1] << 16),
                                    (unsigned)hw[2] | ((unsigned)hw[3] << 16));
                }
            }
        __syncthreads();
        unsigned short* outT = (unsigned short*)outv;
#pragma unroll
        for (int k = 0; k < 8; ++k) {           // 2 rows per iteration
            int idx = k * 256 + tid;
            int row = idx >> 7, rem = idx & 127;
            int col = rem >> 3, u = rem & 7;
            int px = row * 16 + col;
            uint4 v = *(uint4*)&sT16[px * 64 + (u ^ (px & 7)) * 8];
            *(uint4*)(outT + zbase + ((size_t)((y0 + row) * 256 + x0 + col)) * 64 + u * 8) = v;
        }
    } else {
        // final conv: + residual, fp32 NCHW out
        float* outF = (float*)outv;
#pragma unroll
        for (int ot = 0; ot < 2; ++ot)
#pragma unroll
            for (int pt = 0; pt < 2; ++pt) {
                int p = wv * 64 + pt * 32 + l31;
                int y = y0 + (p >> 4), x = x0 + (p & 15);
                size_t pbase = (size_t)b * 64 * HW + (size_t)y * 256 + x;
#pragma unroll
                for (int r = 0; r < 16; ++r) {
                    int oc = ot * 32 + (r & 3) + 8 * (r >> 2) + 4 * half;
                    float v = acc[ot][pt][r] + sB[oc];
                    v += res[pbase + (size_t)oc * HW];
                    outF[pbase + (size_t)oc * HW] = v;
                }
            }
    }
}

// ---------------------------------------------------------------------------
// k_jbfm: fused kg_w5 (C->576) + dynamic-kernel combine.
// y4 NHWC bf16 in; img fp32 NCHW (exact patches); NHWC bf16 out.
// Patches staged per kk as packed bf16 row-pairs: one b32 read feeds both
// pt pixels (vertically adjacent rows).
// ---------------------------------------------------------------------------
__global__ __launch_bounds__(256, 2) void k_jbfm(
    const unsigned short* __restrict__ y4, const float* __restrict__ img,
    const unsigned short* __restrict__ w5T, const float* __restrict__ b5,
    unsigned short* __restrict__ out)
{
    __shared__ __align__(16) char smem[58880];
    uint4* sY  = (uint4*)smem;                   // 2304 uint4: [px][ig 0..8(pad)]
    uint4* sW5 = (uint4*)(smem + 36864);         // 512 uint4: [ig][cc]
    unsigned* sP = (unsigned*)(smem + 45056);    // 2880 u32: [ch8][rp9][col40]
    float* sB5 = (float*)(smem + 56576);         // 576 f32
    unsigned short* sT16 = (unsigned short*)smem;// epilogue overlay 32KB

    int tid = threadIdx.x;
    int wv = tid >> 6, lane = tid & 63;
    int half = lane >> 5, l31 = lane & 31;
    int b = blockIdx.z;
    int y0 = blockIdx.y * 8, x0 = blockIdx.x * 32;
    size_t zbase = (size_t)b * HW * 64;          // NHWC base
    size_t ibase = (size_t)b * 64 * HW;          // NCHW base (img)

    // stage y4 tile: 2048 uint4, NHWC
#pragma unroll
    for (int i = 0; i < 8; ++i) {
        int e = i * 256 + tid;
        int px = e >> 3, ig = e & 7;
        int gy = y0 + (px >> 5), gx = x0 + (px & 31);
        sY[px * 9 + ig] = *(const uint4*)(y4 + zbase + ((size_t)(gy * 256 + gx)) * 64 + ig * 8);
    }
    for (int e = tid; e < 576; e += 256) sB5[e] = b5[e];

    float jb[2][2][16];
#pragma unroll
    for (int i = 0; i < 2; ++i)
#pragma unroll
        for (int j = 0; j < 2; ++j)
#pragma unroll
            for (int r = 0; r < 16; ++r) jb[i][j][r] = 0.f;

#pragma unroll
    for (int kk = 0; kk < 9; ++kk) {
        const int chlo = (kk * 64) / 9;
        __syncthreads();
        for (int u = tid; u < 512; u += 256) {
            int cc = u & 63, ig = u >> 6;
            sW5[u] = ((const uint4*)w5T)[(kk * 64 + cc) * 8 + ig];
        }
        // stage packed patch row-pairs: 720 x (2 float4 -> uint4)
#pragma unroll
        for (int i = 0; i < 3; ++i) {
            int e = i * 256 + tid;
            if (e < 720) {
                int ch = e / 90, rem = e - ch * 90;
                int rp = rem / 10, seg = rem - rp * 10;
                int gy = y0 + rp - 1;
                int gxb = x0 - 4 + seg * 4;
                bool xok = (gxb >= 0 && gxb < 256);
                float4 fa = make_float4(0, 0, 0, 0), fb = make_float4(0, 0, 0, 0);
                const float* rowp = img + ibase + (size_t)(chlo + ch) * HW + gxb;
                if (xok && gy >= 0 && gy < 256)     fa = *(const float4*)(rowp + (size_t)gy * 256);
                if (xok && gy + 1 >= 0 && gy + 1 < 256) fb = *(const float4*)(rowp + (size_t)(gy + 1) * 256);
                uint4 pk;
                pk.x = (unsigned)f2bf(fa.x) | ((unsigned)f2bf(fb.x) << 16);
                pk.y = (unsigned)f2bf(fa.y) | ((unsigned)f2bf(fb.y) << 16);
                pk.z = (unsigned)f2bf(fa.z) | ((unsigned)f2bf(fb.z) << 16);
                pk.w = (unsigned)f2bf(fa.w) | ((unsigned)f2bf(fb.w) << 16);
                *(uint4*)&sP[ch * 360 + rp * 40 + seg * 4] = pk;
            }
        }
        __syncthreads();

        // bias-init accumulators
        f32x16 acc[2][2];
#pragma unroll
        for (int ot = 0; ot < 2; ++ot)
#pragma unroll
            for (int r = 0; r < 16; ++r) {
                int cc0 = ot * 32 + (r & 3) + 8 * (r >> 2);
                float bv = sB5[kk * 64 + cc0 + 4 * half];
                acc[ot][0][r] = bv;
                acc[ot][1][r] = bv;
            }

#pragma unroll
        for (int c = 0; c < 4; ++c) {
            int ig = c * 2 + half;
            bf16x8 a0 = ld_frag(&sW5[ig * 64 + l31]);
            bf16x8 a1 = ld_frag(&sW5[ig * 64 + 32 + l31]);
            int p0 = wv * 64 + l31;
            bf16x8 b0 = ld_frag(&sY[p0 * 9 + ig]);
            bf16x8 b1 = ld_frag(&sY[(p0 + 32) * 9 + ig]);
            acc[0][0] = __builtin_amdgcn_mfma_f32_32x32x16_bf16(a0, b0, acc[0][0], 0, 0, 0);
            acc[0][1] = __builtin_amdgcn_mfma_f32_32x32x16_bf16(a0, b1, acc[0][1], 0, 0, 0);
            acc[1][0] = __builtin_amdgcn_mfma_f32_32x32x16_bf16(a1, b0, acc[1][0], 0, 0, 0);
            acc[1][1] = __builtin_amdgcn_mfma_f32_32x32x16_bf16(a1, b1, acc[1][1], 0, 0, 0);
        }

        // combine: one packed b32 read serves both pt pixels
        {
            const unsigned* basep = sP + wv * 80 + l31 + 3;   // + wv*2*40 + col + 3
#pragma unroll
            for (int ot = 0; ot < 2; ++ot)
#pragma unroll
                for (int r = 0; r < 16; ++r) {
                    const int cc0 = ot * 32 + (r & 3) + 8 * (r >> 2);
                    const int q0 = kk * 64 + cc0, q1 = q0 + 4;
                    const int o0 = (q0 / 9 - chlo) * 360 + (q0 % 9 / 3) * 40 + q0 % 9 % 3;
                    const int o1 = (q1 / 9 - chlo) * 360 + (q1 % 9 / 3) * 40 + q1 % 9 % 3;
                    unsigned pv = basep[half ? o1 : o0];
                    jb[ot][0][r] = fmaf(acc[ot][0][r], bflo2f(pv), jb[ot][0][r]);
                    jb[ot][1][r] = fmaf(acc[ot][1][r], bfhi2f(pv), jb[ot][1][r]);
                }
        }
    }

    // epilogue: NHWC bf16 out via swizzled LDS transpose
    __syncthreads();
#pragma unroll
    for (int ot = 0; ot < 2; ++ot)
#pragma unroll
        for (int pt = 0; pt < 2; ++pt) {
            int px = wv * 64 + pt * 32 + l31;
#pragma unroll
            for (int q2 = 0; q2 < 4; ++q2) {
                unsigned short hw[4];
#pragma unroll
                for (int j = 0; j < 4; ++j) {
                    int r = (q2 << 2) | j;
                    hw[j] = f2bf(jb[ot][pt][r]);
                }
                int unit = ot * 4 + q2;
                int up = unit ^ (px & 7);
                uint2* p = (uint2*)&sT16[px * 64 + up * 8 + half * 4];
                *p = make_uint2((unsigned)hw[0] | ((unsigned)hw[1] << 16),
                                (unsigned)hw[2] | ((unsigned)hw[3] << 16));
            }
        }
    __syncthreads();
#pragma unroll
    for (int k = 0; k < 8; ++k) {
        int col = tid >> 3, u = tid & 7;
        int px = k * 32 + col;
        uint4 v = *(uint4*)&sT16[px * 64 + (u ^ (px & 7)) * 8];
        *(uint4*)(out + zbase + ((size_t)((y0 + k) * 256 + x0 + col)) * 64 + u * 8) = v;
    }
}

// ---------------------------------------------------------------------------
extern "C" void kernel_launch(void* const* d_in, const int* in_sizes, int n_in,
                              void* d_out, int out_size, void* d_ws, size_t ws_size,
                              hipStream_t stream) {
    const float* img  = (const float*)d_in[0];
    const float* gd   = (const float*)d_in[1];
    const float* tw   = (const float*)d_in[2];
    const float* tb   = (const float*)d_in[3];
    const float* ajbf = (const float*)d_in[4];
    const float* kw1  = (const float*)d_in[5];
    const float* kb1  = (const float*)d_in[6];
    const float* kw2  = (const float*)d_in[7];
    const float* kb2  = (const float*)d_in[8];
    const float* kw3  = (const float*)d_in[9];
    const float* kb3  = (const float*)d_in[10];
    const float* kw4  = (const float*)d_in[11];
    const float* kb4  = (const float*)d_in[12];
    const float* kw5  = (const float*)d_in[13];
    const float* kb5  = (const float*)d_in[14];
    const float* akg  = (const float*)d_in[15];
    const float* jw1  = (const float*)d_in[16];
    const float* jb1  = (const float*)d_in[17];
    const float* jw2  = (const float*)d_in[18];
    const float* jb2  = (const float*)d_in[19];
    float* out  = (float*)d_out;

    const size_t TEN = (size_t)2 * HW * 64;      // elements per bf16 tensor
    unsigned short* bufA = (unsigned short*)d_ws;
    unsigned short* imgT = bufA + TEN;
    unsigned short* gdT  = imgT + TEN;
    unsigned short* wT   = gdT + TEN;
    unsigned short* bufB = (unsigned short*)d_out;   // d_out as scratch until final conv

    dim3 g3(16, 16, 2);     // conv tiles 16x16
    dim3 gw(8, 32, 2);      // fuse/jbf tiles 32x8

    k_tr<<<dim3(1024, 4), 256, 0, stream>>>(img, gd, imgT, gdT);
    k_wprep<<<dim3(4, 8), 256, 0, stream>>>(kw1, kw2, kw3, kw4, jw1, jw2, kw5, tw, wT);

    k_fusem<<<gw, 256, 0, stream>>>(imgT, gdT, wT + (size_t)7 * 36864, tb, ajbf, bufA);

    k_conv3m<0><<<g3, 256, 0, stream>>>(bufA, wT + (size_t)0 * 36864, kb1, akg, nullptr, bufB);
    k_conv3m<0><<<g3, 256, 0, stream>>>(bufB, wT + (size_t)1 * 36864, kb2, akg, nullptr, bufA);
    k_conv3m<0><<<g3, 256, 0, stream>>>(bufA, wT + (size_t)2 * 36864, kb3, akg, nullptr, bufB);
    k_conv3m<0><<<g3, 256, 0, stream>>>(bufB, wT + (size_t)3 * 36864, kb4, akg, nullptr, bufA);

    k_jbfm<<<gw, 256, 0, stream>>>(bufA, img, wT + (size_t)6 * 36864, kb5, bufB);

    k_conv3m<0><<<g3, 256, 0, stream>>>(bufB, wT + (size_t)4 * 36864, jb1, ajbf, nullptr, bufA);
    k_conv3m<2><<<g3, 256, 0, stream>>>(bufA, wT + (size_t)5 * 36864, jb2, ajbf, img, out);
}